// Round 5
// baseline (286.802 us; speedup 1.0000x reference)
//
#include <hip/hip_runtime.h>
#include <math.h>

#define BB 4
#define RR 8192
#define SS 32
#define IN_DIM 180
#define SLOT_DIM 1536
#define ATT 1536

// ---------------------------------------------------------------------------
// K1: k_ws[b][s][a] += sum_{i in chunk} slot[b][s][i] * Wk[i][a]
// grid (16 s-pairs, 6 a-tiles of 256, 8 i-chunks of 192), block 256.
// NEW vs R4: TWO s per block -> Wk L2/L3 re-reads halve (302 -> 151 MB).
// Staging stays row-major coalesced (R2's s=4 failure was its uncoalesced
// gather + 384-block grid; here: 6 coalesced copy iters, 768 blocks = 3/CU,
// FMA chain depth 8). sl[ii][8]: g = sp*4+b -> two broadcast b128 reads/iter.
// k_ws must be zeroed before launch (atomic accumulation over i-chunks).
// ---------------------------------------------------------------------------
__global__ __launch_bounds__(256) void k_proj_kernel(const float* __restrict__ slot,
                                                     const float* __restrict__ Wk,
                                                     float* __restrict__ k_ws) {
    const int ICH = 192;
    __shared__ __align__(16) float sl[ICH * 8];  // 6 KB, [ii][sp*4+b]
    const int s0 = blockIdx.x * 2;
    const int a0 = blockIdx.y * 256;
    const int i0 = blockIdx.z * ICH;
    const int t  = threadIdx.x;

    // 8 source rows (b, sp), each 192 contiguous floats: coalesced reads.
    for (int idx = t; idx < 8 * ICH; idx += 256) {
        int g  = idx / ICH;            // 0..7
        int ii = idx - g * ICH;
        int b = g >> 1, sp = g & 1;
        sl[ii * 8 + (sp * 4 + b)] =
            slot[((size_t)(b * SS + s0 + sp)) * SLOT_DIM + i0 + ii];
    }
    __syncthreads();

    float a0c = 0.f, a1c = 0.f, a2c = 0.f, a3c = 0.f;   // sp = 0, b0..3
    float b0c = 0.f, b1c = 0.f, b2c = 0.f, b3c = 0.f;   // sp = 1, b0..3
    const int a = a0 + t;
    const float* wkp = Wk + (size_t)i0 * ATT + a;
#pragma unroll 8
    for (int ii = 0; ii < ICH; ++ii) {
        float wk = wkp[(size_t)ii * ATT];
        const float4 sA = *(const float4*)(sl + ii * 8);      // broadcast
        const float4 sB = *(const float4*)(sl + ii * 8 + 4);  // broadcast
        a0c += sA.x * wk; a1c += sA.y * wk; a2c += sA.z * wk; a3c += sA.w * wk;
        b0c += sB.x * wk; b1c += sB.y * wk; b2c += sB.z * wk; b3c += sB.w * wk;
    }
    atomicAdd(&k_ws[((size_t)(0 * SS + s0)) * ATT + a], a0c);
    atomicAdd(&k_ws[((size_t)(1 * SS + s0)) * ATT + a], a1c);
    atomicAdd(&k_ws[((size_t)(2 * SS + s0)) * ATT + a], a2c);
    atomicAdd(&k_ws[((size_t)(3 * SS + s0)) * ATT + a], a3c);
    atomicAdd(&k_ws[((size_t)(0 * SS + s0 + 1)) * ATT + a], b0c);
    atomicAdd(&k_ws[((size_t)(1 * SS + s0 + 1)) * ATT + a], b1c);
    atomicAdd(&k_ws[((size_t)(2 * SS + s0 + 1)) * ATT + a], b2c);
    atomicAdd(&k_ws[((size_t)(3 * SS + s0 + 1)) * ATT + a], b3c);
}

// ---------------------------------------------------------------------------
// K2: M_ws[b][i][s] = scale * sum_a Wq[i][a] * k_ws[b][s][a]  [R4-exact]
// grid (32 bs-groups of 4, 45 i-groups of 4), block 256 = 4 waves.
// ---------------------------------------------------------------------------
__global__ __launch_bounds__(256) void m_kernel(const float* __restrict__ Wq,
                                                const float* __restrict__ k_ws,
                                                float* __restrict__ M_ws) {
    __shared__ __align__(16) float kr[4 * ATT];  // 24 KB, rows bs0..bs0+3
    const int bs0 = blockIdx.x * 4;
    const int t   = threadIdx.x;

    {
        const float4* src = (const float4*)(k_ws + (size_t)bs0 * ATT);
        float4* dst = (float4*)kr;
        for (int idx = t; idx < 4 * ATT / 4; idx += 256) dst[idx] = src[idx];
    }
    __syncthreads();

    const int wave = t >> 6, lane = t & 63;
    const int i = blockIdx.y * 4 + wave;  // 45*4 = 180
    const float scale = 0.0255155181f;    // 1536^-0.5

    const float* wq = Wq + (size_t)i * ATT;
    float p0 = 0.f, p1 = 0.f, p2 = 0.f, p3 = 0.f;
#pragma unroll
    for (int j = 0; j < ATT / 256; ++j) {          // 6 iters
        const int a = lane * 4 + j * 256;
        const float4 w4 = *(const float4*)(wq + a);
        const float4 k0 = *(const float4*)(kr + 0 * ATT + a);
        const float4 k1 = *(const float4*)(kr + 1 * ATT + a);
        const float4 k2 = *(const float4*)(kr + 2 * ATT + a);
        const float4 k3 = *(const float4*)(kr + 3 * ATT + a);
        p0 += w4.x * k0.x + w4.y * k0.y + w4.z * k0.z + w4.w * k0.w;
        p1 += w4.x * k1.x + w4.y * k1.y + w4.z * k1.z + w4.w * k1.w;
        p2 += w4.x * k2.x + w4.y * k2.y + w4.z * k2.z + w4.w * k2.w;
        p3 += w4.x * k3.x + w4.y * k3.y + w4.z * k3.z + w4.w * k3.w;
    }
    for (int m = 32; m >= 1; m >>= 1) {
        p0 += __shfl_xor(p0, m, 64);
        p1 += __shfl_xor(p1, m, 64);
        p2 += __shfl_xor(p2, m, 64);
        p3 += __shfl_xor(p3, m, 64);
    }
    if (lane == 0) {
        const int b = bs0 >> 5;            // bs0 multiple of 4 -> no b straddle
        const int s = bs0 & (SS - 1);
        float* mp = M_ws + ((size_t)b * IN_DIM + i) * SS + s;
        mp[0] = p0 * scale;
        mp[1] = p1 * scale;
        mp[2] = p2 * scale;
        mp[3] = p3 * scale;
    }
}

// ---------------------------------------------------------------------------
// K3: dots = x @ M -> softmax over s -> write w.  [R4-exact]
// grid (R/64, B), block 256. Wave-parallel softmax (4 threads/row via LDS wt).
// ---------------------------------------------------------------------------
__global__ __launch_bounds__(256) void attn_w_kernel(const float* __restrict__ x,
                                                     const float* __restrict__ M_ws,
                                                     float* __restrict__ w_out) {
    const int TR = 64;
    __shared__ __align__(16) float xs[TR * IN_DIM];   // 46 KB
    __shared__ __align__(16) float wt[TR * 33];       // padded, 8.4 KB
    const int b  = blockIdx.y;
    const int r0 = blockIdx.x * TR;
    const int t  = threadIdx.x;

    {
        const float4* src = (const float4*)(x + ((size_t)b * RR + r0) * IN_DIM);
        float4* dst = (float4*)xs;
        for (int idx = t; idx < TR * IN_DIM / 4; idx += 256) dst[idx] = src[idx];
    }
    __syncthreads();

    const float* Mg = M_ws + (size_t)b * IN_DIM * SS;
    const int rp = t >> 3;             // 0..31 -> rows 2*rp, 2*rp+1
    const int sq = (t & 7) * 4;
    const int ra = rp * 2, rb = ra + 1;
    float4 A = make_float4(0.f, 0.f, 0.f, 0.f);
    float4 Bv = make_float4(0.f, 0.f, 0.f, 0.f);
#pragma unroll 4
    for (int i = 0; i < IN_DIM; ++i) {
        float x0 = xs[ra * IN_DIM + i];
        float x1 = xs[rb * IN_DIM + i];
        const float4 m4 = *(const float4*)(Mg + i * SS + sq);
        A.x += x0 * m4.x; A.y += x0 * m4.y; A.z += x0 * m4.z; A.w += x0 * m4.w;
        Bv.x += x1 * m4.x; Bv.y += x1 * m4.y; Bv.z += x1 * m4.z; Bv.w += x1 * m4.w;
    }
    wt[ra * 33 + sq + 0] = A.x;  wt[ra * 33 + sq + 1] = A.y;
    wt[ra * 33 + sq + 2] = A.z;  wt[ra * 33 + sq + 3] = A.w;
    wt[rb * 33 + sq + 0] = Bv.x; wt[rb * 33 + sq + 1] = Bv.y;
    wt[rb * 33 + sq + 2] = Bv.z; wt[rb * 33 + sq + 3] = Bv.w;
    __syncthreads();

    {
        const int row = t >> 2;
        const int j0  = (t & 3) * 8;
        float* wr = wt + row * 33 + j0;
        float mx = -1e30f;
#pragma unroll
        for (int j = 0; j < 8; ++j) mx = fmaxf(mx, wr[j]);
        mx = fmaxf(mx, __shfl_xor(mx, 1, 64));
        mx = fmaxf(mx, __shfl_xor(mx, 2, 64));
        float sum = 0.f;
#pragma unroll
        for (int j = 0; j < 8; ++j) {
            float e = __expf(wr[j] - mx);
            wr[j] = e;
            sum += e;
        }
        sum += __shfl_xor(sum, 1, 64);
        sum += __shfl_xor(sum, 2, 64);
        float inv = 1.0f / sum;
#pragma unroll
        for (int j = 0; j < 8; ++j) wr[j] *= inv;
    }
    __syncthreads();

    float* wg = w_out + ((size_t)b * RR + r0) * SS;
    for (int idx = t; idx < TR * SS; idx += 256) {
        int rr = idx >> 5, ss = idx & 31;
        wg[idx] = wt[rr * 33 + ss];
    }
}

// ---------------------------------------------------------------------------
// K4: s_out[b][r][d] = sum_s w[b][r][s] * slot[b][s][d]  [R4-exact]
// grid (R/64, 1536/256, B), block 256. Thread = 16 rows x 4 cols: slot read
// one conflict-free b128 (wave reads 1 KB contiguous), w reads wave-uniform
// broadcast, stores 1 KB/instr.
// ---------------------------------------------------------------------------
__global__ __launch_bounds__(256) void out_kernel(const float* __restrict__ slot,
                                                  const float* __restrict__ w_g,
                                                  float* __restrict__ out) {
    const int TRO = 64, TD = 256, WP = 68;
    __shared__ __align__(16) float wtT[SS * WP];  // 8.7 KB, [ss][r] pad 68
    __shared__ __align__(16) float st[SS * TD];   // 32 KB, [ss][d]
    const int b  = blockIdx.z;
    const int r0 = blockIdx.x * TRO;
    const int d0 = blockIdx.y * TD;
    const int t  = threadIdx.x;

    {
        const float4* src = (const float4*)(w_g + ((size_t)b * RR + r0) * SS);
#pragma unroll
        for (int k = 0; k < 2; ++k) {
            int idx = t + k * 256;                 // 0..511
            int rr = idx >> 3, ssq = (idx & 7) * 4;
            float4 f = src[idx];
            wtT[(ssq + 0) * WP + rr] = f.x;
            wtT[(ssq + 1) * WP + rr] = f.y;
            wtT[(ssq + 2) * WP + rr] = f.z;
            wtT[(ssq + 3) * WP + rr] = f.w;
        }
    }
#pragma unroll
    for (int k = 0; k < 8; ++k) {
        int idx = t + k * 256;                     // 0..2047
        int row = idx >> 6, c4 = (idx & 63) * 4;   // row 0..31, c4 0..252
        *(float4*)(st + row * TD + c4) =
            *(const float4*)(slot + ((size_t)(b * SS + row)) * SLOT_DIM + d0 + c4);
    }
    __syncthreads();

    const int d  = (t & 63) * 4;       // 0..252: wave covers 256 cols contiguously
    const int rg = (t >> 6) * 16;      // 16 rows per thread, uniform per wave
    float4 acc[16];
#pragma unroll
    for (int r = 0; r < 16; ++r) acc[r] = make_float4(0.f, 0.f, 0.f, 0.f);

#pragma unroll 4
    for (int ss = 0; ss < SS; ++ss) {
        const float4 v  = *(const float4*)(st + ss * TD + d);
        const float4 w0 = *(const float4*)(wtT + ss * WP + rg);
        const float4 w1 = *(const float4*)(wtT + ss * WP + rg + 4);
        const float4 w2 = *(const float4*)(wtT + ss * WP + rg + 8);
        const float4 w3 = *(const float4*)(wtT + ss * WP + rg + 12);
        const float wr[16] = {w0.x, w0.y, w0.z, w0.w, w1.x, w1.y, w1.z, w1.w,
                              w2.x, w2.y, w2.z, w2.w, w3.x, w3.y, w3.z, w3.w};
#pragma unroll
        for (int r = 0; r < 16; ++r) {
            acc[r].x += wr[r] * v.x;
            acc[r].y += wr[r] * v.y;
            acc[r].z += wr[r] * v.z;
            acc[r].w += wr[r] * v.w;
        }
    }

#pragma unroll
    for (int r = 0; r < 16; ++r) {
        *(float4*)(out + ((size_t)b * RR + r0 + rg + r) * SLOT_DIM + d0 + d) = acc[r];
    }
}

// ---------------------------------------------------------------------------
extern "C" void kernel_launch(void* const* d_in, const int* in_sizes, int n_in,
                              void* d_out, int out_size, void* d_ws, size_t ws_size,
                              hipStream_t stream) {
    const float* x    = (const float*)d_in[0];  // [4, 8192, 180]
    const float* slot = (const float*)d_in[1];  // [4, 32, 1536]
    const float* Wq   = (const float*)d_in[2];  // [180, 1536]
    const float* Wk   = (const float*)d_in[3];  // [1536, 1536]

    float* out   = (float*)d_out;                        // s: [4, 8192, 1536]
    float* w_out = out + (size_t)BB * RR * SLOT_DIM;     // w: [4, 8192, 32]

    float* k_ws = (float*)d_ws;                          // [4, 32, 1536]
    float* M_ws = k_ws + (size_t)BB * SS * ATT;          // [4, 180, 32]

    // k_ws is accumulated with atomics -> zero it (ws is poisoned 0xAA).
    hipMemsetAsync(k_ws, 0, (size_t)BB * SS * ATT * sizeof(float), stream);

    k_proj_kernel<<<dim3(SS / 2, ATT / 256, SLOT_DIM / 192), 256, 0, stream>>>(slot, Wk, k_ws);
    m_kernel<<<dim3(BB * SS / 4, IN_DIM / 4), 256, 0, stream>>>(Wq, k_ws, M_ws);
    attn_w_kernel<<<dim3(RR / 64, BB), 256, 0, stream>>>(x, M_ws, w_out);
    out_kernel<<<dim3(RR / 64, SLOT_DIM / 256, BB), 256, 0, stream>>>(slot, w_out, out);
}